// Round 14
// baseline (205.911 us; speedup 1.0000x reference)
//
#include <hip/hip_runtime.h>
#include <math.h>

#define NPTS 65536
#define DIM 64
#define NCODE 1024

typedef float f32x4 __attribute__((ext_vector_type(4)));
typedef short bf16x8 __attribute__((ext_vector_type(8)));

// output layout (flat float32 concat, reference return order)
#define OFF_LOSS 0ull
#define OFF_Q    1ull
#define OFF_PERP 4194305ull
#define OFF_ENC  4194306ull
#define OFF_IDX  71303170ull

__device__ __forceinline__ unsigned short bf16hi(float f) {
    unsigned u = __float_as_uint(f);
    unsigned r = u + 0x7FFFu + ((u >> 16) & 1u);   // RNE truncate to bf16
    return (unsigned short)(r >> 16);
}
__device__ __forceinline__ float bf16tof(unsigned short h) {
    return __uint_as_float(((unsigned)h) << 16);
}

// 8 consecutive fp32 (16B-aligned) -> hi/lo bf16x8
__device__ __forceinline__ void cvt8(const float* p, bf16x8& hi, bf16x8& lo) {
    float4 a = *(const float4*)p;
    float4 b = *(const float4*)(p + 4);
    float v[8] = {a.x, a.y, a.z, a.w, b.x, b.y, b.z, b.w};
#pragma unroll
    for (int i = 0; i < 8; ++i) {
        unsigned short h = bf16hi(v[i]);
        hi[i] = (short)h;
        lo[i] = (short)bf16hi(v[i] - bf16tof(h));
    }
}
__device__ __forceinline__ void cvt8v(float4 a, float4 b, bf16x8& hi, bf16x8& lo) {
    float v[8] = {a.x, a.y, a.z, a.w, b.x, b.y, b.z, b.w};
#pragma unroll
    for (int i = 0; i < 8; ++i) {
        unsigned short h = bf16hi(v[i]);
        hi[i] = (short)h;
        lo[i] = (short)bf16hi(v[i] - bf16tof(h));
    }
}

// ---------------- wave-autonomous: 1 wave = 16 points, full 1024-code scan ----------------
// r10's scan math per wave but NO cross-wave merge, NO expensive barrier drains:
// the two __syncthreads sit where <=4 vmem ops are outstanding. The 80 fat
// stores (one-hot 64KB + q 4KB per wave) are issued at the END and drain while
// the dispatcher launches QUEUED blocks (grid 4096, resident capped at 8/CU by
// dynamic-LDS padding -> 2048 queued). That queue converts the old lockstep
// [all-scan][all-write] (45+50us) into scan-overlapping-write (~max+ramp).
// Plain (not NT) enc stores: waves retire at L2-ack, not HBM drain.
// dist = e2 - 2*(xh.eh + xh.el + xl.eh), exact fp32 e2 inline (matches ref,
// absmax 0 through r13); packed-u64 argmin = exact first-min tie-break.
__global__ __launch_bounds__(64) void vq_wave(const float* __restrict__ in,
                                              const float* __restrict__ emb,
                                              float* __restrict__ out,
                                              unsigned int* __restrict__ hist,
                                              float* __restrict__ loss_acc) {
    extern __shared__ float smem[];                 // 19456B pad -> 8 blocks/CU
    float (*lds_x)[68] = (float (*)[68])smem;       // [16][68] fp32 x-tile
    int* lds_idx = (int*)(smem + 16 * 68);          // [16]

    const int lane = threadIdx.x;                   // 0..63
    const int P0   = blockIdx.x * 16;               // 4096 tiles of 16 points
    const int b    = P0 >> 12;
    const int h    = (P0 >> 6) & 63;
    const int w0   = P0 & 63;                       // 0/16/32/48

    // ---- stage x: lane = dim d; 16 consecutive w as 4x float4 -> lds[w][d] ----
    {
        const float* rowp = in + (size_t)b * (DIM * 4096) + (size_t)lane * 4096 + h * 64 + w0;
#pragma unroll
        for (int j = 0; j < 4; ++j) {
            float4 v = *(const float4*)(rowp + j * 4);
            lds_x[j * 4 + 0][lane] = v.x;
            lds_x[j * 4 + 1][lane] = v.y;
            lds_x[j * 4 + 2][lane] = v.z;
            lds_x[j * 4 + 3][lane] = v.w;
        }
    }
    __syncthreads();   // single wave; x loads already consumed -> cheap

    const int m15 = lane & 15;
    const int g4  = lane >> 4;
    const int kb  = g4 * 8;                          // this lane's k-slice base

    // A fragments: one 16-pt tile resident (A row = lane&15, k = kb..)
    bf16x8 Ahi0, Ahi1, Alo0, Alo1;
    cvt8(&lds_x[m15][kb],      Ahi0, Alo0);
    cvt8(&lds_x[m15][kb + 32], Ahi1, Alo1);

    float best[4];
    int   bestk[4];
#pragma unroll
    for (int r = 0; r < 4; ++r) { best[r] = INFINITY; bestk[r] = 0; }

#pragma unroll 4
    for (int ct = 0; ct < 64; ++ct) {
        const int code = ct * 16 + m15;              // B col = lane&15
        const float* ep = emb + (size_t)code * DIM + kb;
        float4 e0 = *(const float4*)ep;
        float4 e1 = *(const float4*)(ep + 4);
        float4 e2a = *(const float4*)(ep + 32);
        float4 e3 = *(const float4*)(ep + 36);

        // ||e||^2: 16 local squares, then sum the 4 k-slices (xor keeps m15)
        float sq = e0.x * e0.x;
        sq = fmaf(e0.y, e0.y, sq); sq = fmaf(e0.z, e0.z, sq); sq = fmaf(e0.w, e0.w, sq);
        sq = fmaf(e1.x, e1.x, sq); sq = fmaf(e1.y, e1.y, sq); sq = fmaf(e1.z, e1.z, sq); sq = fmaf(e1.w, e1.w, sq);
        sq = fmaf(e2a.x, e2a.x, sq); sq = fmaf(e2a.y, e2a.y, sq); sq = fmaf(e2a.z, e2a.z, sq); sq = fmaf(e2a.w, e2a.w, sq);
        sq = fmaf(e3.x, e3.x, sq); sq = fmaf(e3.y, e3.y, sq); sq = fmaf(e3.z, e3.z, sq); sq = fmaf(e3.w, e3.w, sq);
        sq += __shfl_xor(sq, 16, 64);
        sq += __shfl_xor(sq, 32, 64);
        const float e2v = sq;

        bf16x8 Bhi0, Blo0, Bhi1, Blo1;
        cvt8v(e0, e1, Bhi0, Blo0);
        cvt8v(e2a, e3, Bhi1, Blo1);

        // two independent 3-chains (only 1 pt-tile -> need the ILP split)
        f32x4 aa = {0.f, 0.f, 0.f, 0.f};
        f32x4 ab = {0.f, 0.f, 0.f, 0.f};
        aa = __builtin_amdgcn_mfma_f32_16x16x32_bf16(Ahi0, Bhi0, aa, 0, 0, 0);
        ab = __builtin_amdgcn_mfma_f32_16x16x32_bf16(Ahi1, Bhi1, ab, 0, 0, 0);
        aa = __builtin_amdgcn_mfma_f32_16x16x32_bf16(Ahi0, Blo0, aa, 0, 0, 0);
        ab = __builtin_amdgcn_mfma_f32_16x16x32_bf16(Ahi1, Blo1, ab, 0, 0, 0);
        aa = __builtin_amdgcn_mfma_f32_16x16x32_bf16(Alo0, Bhi0, aa, 0, 0, 0);
        ab = __builtin_amdgcn_mfma_f32_16x16x32_bf16(Alo1, Bhi1, ab, 0, 0, 0);
#pragma unroll
        for (int r = 0; r < 4; ++r) {
            float dist = fmaf(-2.0f, aa[r] + ab[r], e2v);
            if (dist < best[r]) { best[r] = dist; bestk[r] = code; }
        }
    }

    // cross-lane argmin over the 16 code-cols, lexicographic (dist, code)
#pragma unroll
    for (int r = 0; r < 4; ++r) {
        unsigned u = __float_as_uint(best[r]);
        u = (u & 0x80000000u) ? ~u : (u | 0x80000000u);   // monotone f32->u32
        unsigned long long key = ((unsigned long long)u << 32) | (unsigned)bestk[r];
#pragma unroll
        for (int sm = 1; sm < 16; sm <<= 1) {
            unsigned long long o = __shfl_xor(key, sm, 16);
            key = (o < key) ? o : key;
        }
        if (m15 == 0) {
            const int pt  = g4 * 4 + r;               // C row = (lane>>4)*4 + r
            const int idx = (int)(key & 0xFFFFFFFFull);
            lds_idx[pt] = idx;
            out[OFF_IDX + P0 + pt] = (float)idx;
            atomicAdd(&hist[idx], 1u);
        }
    }
    __syncthreads();   // only 4 idx stores + 4 atomics outstanding -> cheap drain

    // ---- q_ste + loss: lane (g4,m15) does point m15, dims [16g4,16g4+16) ----
    {
        const int myidx = lds_idx[m15];
        const float* eq = emb + (size_t)myidx * DIM + g4 * 16;
        float* qb = out + OFF_Q + ((size_t)b * 64 + g4 * 16) * 4096 + h * 64 + w0 + m15;
        float lsum = 0.f;
#pragma unroll
        for (int dd = 0; dd < 16; ++dd) {
            float x = lds_x[m15][g4 * 16 + dd];
            float diff = eq[dd] - x;
            lsum = fmaf(diff, diff, lsum);
            qb[(size_t)dd * 4096] = x + diff;         // exact STE form; plain store
        }
        for (int off = 32; off > 0; off >>= 1) lsum += __shfl_down(lsum, off, 64);
        if (lane == 0) atomicAdd(loss_acc, lsum);
    }

    // ---- one-hot: 16 rows x 1024 floats, plain f32x4 (1KB/wave-instruction) ----
    {
        f32x4* enc4 = (f32x4*)(out + OFF_ENC + (unsigned long long)P0 * NCODE);
#pragma unroll
        for (int rr = 0; rr < 16; ++rr) {
            const int target = lds_idx[rr];           // wave-uniform broadcast
#pragma unroll
            for (int k = 0; k < 4; ++k) {
                const int j = k * 64 + lane;          // f32x4 index in row
                const int c0 = j * 4;
                f32x4 v;
                v.x = (c0 + 0 == target) ? 1.0f : 0.0f;
                v.y = (c0 + 1 == target) ? 1.0f : 0.0f;
                v.z = (c0 + 2 == target) ? 1.0f : 0.0f;
                v.w = (c0 + 3 == target) ? 1.0f : 0.0f;
                enc4[(size_t)rr * 256 + j] = v;       // plain: retire at L2 ack
            }
        }
    }
}

// ---------------- finalize: loss scalar + perplexity ----------------
__global__ __launch_bounds__(1024) void vq_finalize(const unsigned int* __restrict__ hist,
                                                    const float* __restrict__ loss_acc,
                                                    float* __restrict__ out) {
    int t = threadIdx.x;
    float c = (float)hist[t];
    float pv = c * (1.0f / (float)NPTS);
    float term = pv * logf(pv + 1e-10f);

    __shared__ float red[16];
    float s = term;
    for (int off = 32; off > 0; off >>= 1) s += __shfl_down(s, off, 64);
    if ((t & 63) == 0) red[t >> 6] = s;
    __syncthreads();
    if (t < 16) {
        float v = red[t];
        for (int off = 8; off > 0; off >>= 1) v += __shfl_down(v, off, 64);
        if (t == 0) {
            out[OFF_PERP] = expf(-v);
            out[OFF_LOSS] = 0.25f * loss_acc[0] * (1.0f / 4194304.0f);
        }
    }
}

extern "C" void kernel_launch(void* const* d_in, const int* in_sizes, int n_in,
                              void* d_out, int out_size, void* d_ws, size_t ws_size,
                              hipStream_t stream) {
    const float* in  = (const float*)d_in[0];   // (16,64,64,64) BCHW
    const float* emb = (const float*)d_in[1];   // (1024,64)
    float* out = (float*)d_out;

    // ws: [0..15] loss_acc f32 | [16..1039] hist u32  (atomics only; no bulk)
    float* ws_f = (float*)d_ws;
    float* loss_acc = ws_f;
    unsigned int* hist = (unsigned int*)d_ws + 16;

    (void)hipMemsetAsync(d_ws, 0, (16 + NCODE) * sizeof(float), stream);

    // dynamic LDS 19456B (needs 4416B) -> exactly 8 blocks/CU resident;
    // grid 4096 -> 2048 queued behind 2048 resident waves = dispatch pipeline.
    vq_wave<<<NPTS / 16, 64, 19456, stream>>>(in, emb, out, hist, loss_acc);
    vq_finalize<<<1, 1024, 0, stream>>>(hist, loss_acc, out);
}

// Round 15
// 191.298 us; speedup vs baseline: 1.0764x; 1.0764x over previous
//
#include <hip/hip_runtime.h>
#include <math.h>

#define NPTS 65536
#define DIM 64
#define NCODE 1024

typedef float f32x2 __attribute__((ext_vector_type(2)));
typedef float f32x4 __attribute__((ext_vector_type(4)));
typedef short bf16x8 __attribute__((ext_vector_type(8)));

// output layout (flat float32 concat, reference return order)
#define OFF_LOSS 0ull
#define OFF_Q    1ull
#define OFF_PERP 4194305ull
#define OFF_ENC  4194306ull
#define OFF_IDX  71303170ull

__device__ __forceinline__ unsigned short bf16hi(float f) {
    unsigned u = __float_as_uint(f);
    unsigned r = u + 0x7FFFu + ((u >> 16) & 1u);   // RNE truncate to bf16
    return (unsigned short)(r >> 16);
}
__device__ __forceinline__ float bf16tof(unsigned short h) {
    return __uint_as_float(((unsigned)h) << 16);
}

// 8 consecutive fp32 (16B-aligned) -> hi/lo bf16x8
__device__ __forceinline__ void cvt8(const float* p, bf16x8& hi, bf16x8& lo) {
    float4 a = *(const float4*)p;
    float4 b = *(const float4*)(p + 4);
    float v[8] = {a.x, a.y, a.z, a.w, b.x, b.y, b.z, b.w};
#pragma unroll
    for (int i = 0; i < 8; ++i) {
        unsigned short h = bf16hi(v[i]);
        hi[i] = (short)h;
        lo[i] = (short)bf16hi(v[i] - bf16tof(h));
    }
}
__device__ __forceinline__ void cvt8v(float4 a, float4 b, bf16x8& hi, bf16x8& lo) {
    float v[8] = {a.x, a.y, a.z, a.w, b.x, b.y, b.z, b.w};
#pragma unroll
    for (int i = 0; i < 8; ++i) {
        unsigned short h = bf16hi(v[i]);
        hi[i] = (short)h;
        lo[i] = (short)bf16hi(v[i] - bf16tof(h));
    }
}

// ---------------- fused: MFMA argmin + q_ste + loss + one-hot ----------------
// Base = r10 (105.4us best). ONLY the scan body schedule changes (traffic
// identical; r12 counters prove FETCH/WRITE are near-ideal already):
//  (1) cvt + all 24 MFMAs issued BEFORE the e2 square-chain, so the serial
//      16-FMA + 2 shfl_xor e2 path overlaps the MFMA pipe instead of sitting
//      on the critical path between B-load and MFMA.
//  (2) per-pt 6-deep MFMA chain split into two independent 3-chains (aa/ab):
//      8 parallel chains per ct. dist = e2 - 2*(aa+ab).
//  (3) e2 squares as 4 independent sub-chains + tree add (dep 16 -> 6).
//  (4) launch_bounds(256,4): live set ~100 VGPR <= 128 -> 4 waves/SIMD.
// Everything else identical to r10 (B inline-cvt from emb d_in = L2-cached,
// d_ws bulk uncached per r5/r6; 4-pt B-amortization essential per r14;
// packed-u64 argmin; NT f32x4 one-hot; plain q stores from LDS x).
__global__ __launch_bounds__(256, 4) void vq_fused(const float* __restrict__ in,
                                                   const float* __restrict__ emb,
                                                   float* __restrict__ out,
                                                   unsigned int* __restrict__ hist,
                                                   float* __restrict__ loss_acc) {
    __shared__ __align__(16) float lds_x[64][68];
    __shared__ unsigned long long cand[4][64];
    __shared__ int s_idx[64];

    const int tid  = threadIdx.x;
    const int lane = tid & 63;
    const int wv   = __builtin_amdgcn_readfirstlane(tid >> 6);

    const int P0 = blockIdx.x * 64;
    const int b  = P0 >> 12;
    const int h  = (P0 >> 6) & 63;
    const float* base = in + (size_t)b * (DIM * 4096) + h * 64;

    // ---- stage x: 64x64 fp32 tile, coalesced load, transpose into LDS ----
    {
        int d  = tid >> 2;
        int wq = tid & 3;
        const float* rowp = base + (size_t)d * 4096 + wq * 16;
#pragma unroll
        for (int j = 0; j < 4; ++j) {
            float4 v = *(const float4*)(rowp + j * 4);
            int w0 = wq * 16 + j * 4;
            lds_x[w0 + 0][d] = v.x;
            lds_x[w0 + 1][d] = v.y;
            lds_x[w0 + 2][d] = v.z;
            lds_x[w0 + 3][d] = v.w;
        }
    }
    __syncthreads();

    const int m15 = lane & 15;
    const int g4  = lane >> 4;
    const int kb  = g4 * 8;            // this lane's k-slice base (8 fp32)
    const int c0w = wv * 256;          // this wave's code slice (ascending)

    // A fragments, all 4 point-tiles resident (A row = lane&15, k = kb..)
    bf16x8 Ahi[4][2], Alo[4][2];
#pragma unroll
    for (int pt = 0; pt < 4; ++pt) {
        int p = pt * 16 + m15;
        cvt8(&lds_x[p][kb],      Ahi[pt][0], Alo[pt][0]);
        cvt8(&lds_x[p][kb + 32], Ahi[pt][1], Alo[pt][1]);
    }

    float best[4][4];
    int   bestk[4][4];
#pragma unroll
    for (int pt = 0; pt < 4; ++pt)
#pragma unroll
        for (int r = 0; r < 4; ++r) { best[pt][r] = INFINITY; bestk[pt][r] = 0; }

    for (int ct = 0; ct < 16; ++ct) {
        const int code = c0w + ct * 16 + m15;          // B col = lane&15
        const float* ep = emb + (size_t)code * DIM + kb;
        float4 e0 = *(const float4*)ep;
        float4 e1 = *(const float4*)(ep + 4);
        float4 e2a = *(const float4*)(ep + 32);
        float4 e3 = *(const float4*)(ep + 36);

        // cvt first, MFMAs issued immediately (e2 runs under the MFMA pipe)
        bf16x8 Bhi0, Blo0, Bhi1, Blo1;
        cvt8v(e0, e1, Bhi0, Blo0);
        cvt8v(e2a, e3, Bhi1, Blo1);

        f32x4 aa[4], ab[4];
#pragma unroll
        for (int pt = 0; pt < 4; ++pt) {
            aa[pt] = (f32x4){0.f, 0.f, 0.f, 0.f};
            ab[pt] = (f32x4){0.f, 0.f, 0.f, 0.f};
        }
#pragma unroll
        for (int pt = 0; pt < 4; ++pt) {
            aa[pt] = __builtin_amdgcn_mfma_f32_16x16x32_bf16(Ahi[pt][0], Bhi0, aa[pt], 0, 0, 0);
            ab[pt] = __builtin_amdgcn_mfma_f32_16x16x32_bf16(Ahi[pt][1], Bhi1, ab[pt], 0, 0, 0);
            aa[pt] = __builtin_amdgcn_mfma_f32_16x16x32_bf16(Ahi[pt][0], Blo0, aa[pt], 0, 0, 0);
            ab[pt] = __builtin_amdgcn_mfma_f32_16x16x32_bf16(Ahi[pt][1], Blo1, ab[pt], 0, 0, 0);
            aa[pt] = __builtin_amdgcn_mfma_f32_16x16x32_bf16(Alo[pt][0], Bhi0, aa[pt], 0, 0, 0);
            ab[pt] = __builtin_amdgcn_mfma_f32_16x16x32_bf16(Alo[pt][1], Bhi1, ab[pt], 0, 0, 0);
        }

        // ||e||^2: 4 independent sub-chains + tree (dep 6), then 2 shfls --
        // all on VALU/LDS pipes while the MFMA pipe drains.
        float s0 = e0.x * e0.x, s1 = e1.x * e1.x, s2 = e2a.x * e2a.x, s3 = e3.x * e3.x;
        s0 = fmaf(e0.y, e0.y, s0); s1 = fmaf(e1.y, e1.y, s1);
        s2 = fmaf(e2a.y, e2a.y, s2); s3 = fmaf(e3.y, e3.y, s3);
        s0 = fmaf(e0.z, e0.z, s0); s1 = fmaf(e1.z, e1.z, s1);
        s2 = fmaf(e2a.z, e2a.z, s2); s3 = fmaf(e3.z, e3.z, s3);
        s0 = fmaf(e0.w, e0.w, s0); s1 = fmaf(e1.w, e1.w, s1);
        s2 = fmaf(e2a.w, e2a.w, s2); s3 = fmaf(e3.w, e3.w, s3);
        float sq = (s0 + s1) + (s2 + s3);
        sq += __shfl_xor(sq, 16, 64);
        sq += __shfl_xor(sq, 32, 64);
        const float e2v = sq;

#pragma unroll
        for (int pt = 0; pt < 4; ++pt) {
#pragma unroll
            for (int r = 0; r < 4; ++r) {
                float dist = fmaf(-2.0f, aa[pt][r] + ab[pt][r], e2v);
                if (dist < best[pt][r]) { best[pt][r] = dist; bestk[pt][r] = code; }
            }
        }
    }

    // per-wave cross-lane argmin over 16 cols, lexicographic (dist, code)
#pragma unroll
    for (int pt = 0; pt < 4; ++pt) {
#pragma unroll
        for (int r = 0; r < 4; ++r) {
            unsigned u = __float_as_uint(best[pt][r]);
            u = (u & 0x80000000u) ? ~u : (u | 0x80000000u);   // monotone f32->u32
            unsigned long long key = ((unsigned long long)u << 32) | (unsigned)bestk[pt][r];
#pragma unroll
            for (int sm = 1; sm < 16; sm <<= 1) {
                unsigned long long o = __shfl_xor(key, sm, 16);
                key = (o < key) ? o : key;
            }
            if (m15 == 0) cand[wv][pt * 16 + g4 * 4 + r] = key;
        }
    }
    __syncthreads();

    if (tid < 64) {   // merge 4 wave-slices (ascending -> first-min tie-break)
        unsigned long long k0 = cand[0][tid];
#pragma unroll
        for (int s = 1; s < 4; ++s) {
            unsigned long long o = cand[s][tid];
            if (o < k0) k0 = o;
        }
        int idx = (int)(k0 & 0xFFFFFFFFull);
        s_idx[tid] = idx;
        out[OFF_IDX + P0 + tid] = (float)idx;
        atomicAdd(&hist[idx], 1u);
    }
    __syncthreads();

    // ---- q_ste + loss: wave wv owns dims [16wv,16wv+16); x from LDS ----
    {
        const int w = lane;
        const int myidx = s_idx[w];
        const float* eq = emb + (size_t)myidx * DIM + wv * 16;
        float* qb = out + OFF_Q + ((size_t)b * 64 + wv * 16) * 4096 + h * 64 + w;
        float lsum = 0.f;
#pragma unroll
        for (int dd = 0; dd < 16; ++dd) {
            float x = lds_x[w][wv * 16 + dd];
            float diff = eq[dd] - x;
            lsum = fmaf(diff, diff, lsum);
            qb[(size_t)dd * 4096] = x + diff;      // exact STE form; plain store
        }
        for (int off = 32; off > 0; off >>= 1) lsum += __shfl_down(lsum, off, 64);
        if (lane == 0) atomicAdd(loss_acc, lsum);
    }

    // ---- one-hot: wave wv owns rows [16wv,16wv+16); 1024B/wave NT stores ----
    {
        f32x4* enc4 = (f32x4*)(out + OFF_ENC + (unsigned long long)P0 * NCODE);
#pragma unroll
        for (int rr = 0; rr < 16; ++rr) {
            const int row = wv * 16 + rr;          // wave-uniform
            const int target = s_idx[row];
#pragma unroll
            for (int k = 0; k < 4; ++k) {
                const int j = k * 64 + lane;       // f32x4 index in row
                const int c0 = j * 4;
                f32x4 v;
                v.x = (c0 + 0 == target) ? 1.0f : 0.0f;
                v.y = (c0 + 1 == target) ? 1.0f : 0.0f;
                v.z = (c0 + 2 == target) ? 1.0f : 0.0f;
                v.w = (c0 + 3 == target) ? 1.0f : 0.0f;
                __builtin_nontemporal_store(v, &enc4[(size_t)row * 256 + j]);
            }
        }
    }
}

// ---------------- finalize: loss scalar + perplexity ----------------
__global__ __launch_bounds__(1024) void vq_finalize(const unsigned int* __restrict__ hist,
                                                    const float* __restrict__ loss_acc,
                                                    float* __restrict__ out) {
    int t = threadIdx.x;
    float c = (float)hist[t];
    float pv = c * (1.0f / (float)NPTS);
    float term = pv * logf(pv + 1e-10f);

    __shared__ float red[16];
    float s = term;
    for (int off = 32; off > 0; off >>= 1) s += __shfl_down(s, off, 64);
    if ((t & 63) == 0) red[t >> 6] = s;
    __syncthreads();
    if (t < 16) {
        float v = red[t];
        for (int off = 8; off > 0; off >>= 1) v += __shfl_down(v, off, 64);
        if (t == 0) {
            out[OFF_PERP] = expf(-v);
            out[OFF_LOSS] = 0.25f * loss_acc[0] * (1.0f / 4194304.0f);
        }
    }
}

extern "C" void kernel_launch(void* const* d_in, const int* in_sizes, int n_in,
                              void* d_out, int out_size, void* d_ws, size_t ws_size,
                              hipStream_t stream) {
    const float* in  = (const float*)d_in[0];   // (16,64,64,64) BCHW
    const float* emb = (const float*)d_in[1];   // (1024,64)
    float* out = (float*)d_out;

    // ws: [0..15] loss_acc f32 | [16..1039] hist u32  (atomics only; no bulk)
    float* ws_f = (float*)d_ws;
    float* loss_acc = ws_f;
    unsigned int* hist = (unsigned int*)d_ws + 16;

    (void)hipMemsetAsync(d_ws, 0, (16 + NCODE) * sizeof(float), stream);

    vq_fused<<<NPTS / 64, 256, 0, stream>>>(in, emb, out, hist, loss_acc);
    vq_finalize<<<1, 1024, 0, stream>>>(hist, loss_acc, out);
}

// Round 16
// 111.795 us; speedup vs baseline: 1.8419x; 1.7112x over previous
//
#include <hip/hip_runtime.h>
#include <math.h>

#define NPTS 65536
#define DIM 64
#define NCODE 1024

typedef float f32x2 __attribute__((ext_vector_type(2)));
typedef float f32x4 __attribute__((ext_vector_type(4)));
typedef short bf16x8 __attribute__((ext_vector_type(8)));

// output layout (flat float32 concat, reference return order)
#define OFF_LOSS 0ull
#define OFF_Q    1ull
#define OFF_PERP 4194305ull
#define OFF_ENC  4194306ull
#define OFF_IDX  71303170ull

__device__ __forceinline__ unsigned short bf16hi(float f) {
    unsigned u = __float_as_uint(f);
    unsigned r = u + 0x7FFFu + ((u >> 16) & 1u);   // RNE truncate to bf16
    return (unsigned short)(r >> 16);
}
__device__ __forceinline__ float bf16tof(unsigned short h) {
    return __uint_as_float(((unsigned)h) << 16);
}

// 8 consecutive fp32 (16B-aligned) -> hi/lo bf16x8
__device__ __forceinline__ void cvt8(const float* p, bf16x8& hi, bf16x8& lo) {
    float4 a = *(const float4*)p;
    float4 b = *(const float4*)(p + 4);
    float v[8] = {a.x, a.y, a.z, a.w, b.x, b.y, b.z, b.w};
#pragma unroll
    for (int i = 0; i < 8; ++i) {
        unsigned short h = bf16hi(v[i]);
        hi[i] = (short)h;
        lo[i] = (short)bf16hi(v[i] - bf16tof(h));
    }
}
__device__ __forceinline__ void cvt8v(float4 a, float4 b, bf16x8& hi, bf16x8& lo) {
    float v[8] = {a.x, a.y, a.z, a.w, b.x, b.y, b.z, b.w};
#pragma unroll
    for (int i = 0; i < 8; ++i) {
        unsigned short h = bf16hi(v[i]);
        hi[i] = (short)h;
        lo[i] = (short)bf16hi(v[i] - bf16tof(h));
    }
}

// ---------------- fused: MFMA argmin + q_ste + loss + one-hot ----------------
// EXACT r10 structure (best, 105.4us) with ONE variable changed: the one-hot
// stores are PLAIN f32x4 instead of nontemporal. Mechanism under test: NT
// stores complete at HBM (bypass L2) -> they occupy vmcnt slots for ~HBM
// latency and the end-of-kernel drain ties wave retirement to HBM; plain
// stores ack at L2 (harness fillBuffer sustains 6.8TB/s on this buffer with
// plain stores). Everything else byte-identical to r10:
//  - x tile fp32 in LDS (transposed), A-frags via register cvt, all 4 pt
//    resident, per-pt MFMA issue-and-consume order (r15 proved keeping 8
//    accs live across the cluster -> scratch spill, FETCH 29->251MB)
//  - B inline-cvt fp32 from emb (d_in = L2-cached; d_ws bulk uncached r5/r6)
//  - inline e2 (16 FMA + 2 shfl_xor)  [cheaper than every hoist tried]
//  - packed-u64 (sortable dist, code) argmin = exact first-min tie-break
//  - q_ste plain stores from LDS x + loss atomic
__global__ __launch_bounds__(256, 3) void vq_fused(const float* __restrict__ in,
                                                   const float* __restrict__ emb,
                                                   float* __restrict__ out,
                                                   unsigned int* __restrict__ hist,
                                                   float* __restrict__ loss_acc) {
    __shared__ __align__(16) float lds_x[64][68];
    __shared__ unsigned long long cand[4][64];
    __shared__ int s_idx[64];

    const int tid  = threadIdx.x;
    const int lane = tid & 63;
    const int wv   = __builtin_amdgcn_readfirstlane(tid >> 6);

    const int P0 = blockIdx.x * 64;
    const int b  = P0 >> 12;
    const int h  = (P0 >> 6) & 63;
    const float* base = in + (size_t)b * (DIM * 4096) + h * 64;

    // ---- stage x: 64x64 fp32 tile, coalesced load, transpose into LDS ----
    {
        int d  = tid >> 2;
        int wq = tid & 3;
        const float* rowp = base + (size_t)d * 4096 + wq * 16;
#pragma unroll
        for (int j = 0; j < 4; ++j) {
            float4 v = *(const float4*)(rowp + j * 4);
            int w0 = wq * 16 + j * 4;
            lds_x[w0 + 0][d] = v.x;
            lds_x[w0 + 1][d] = v.y;
            lds_x[w0 + 2][d] = v.z;
            lds_x[w0 + 3][d] = v.w;
        }
    }
    __syncthreads();

    const int m15 = lane & 15;
    const int g4  = lane >> 4;
    const int kb  = g4 * 8;            // this lane's k-slice base (8 fp32)
    const int c0w = wv * 256;          // this wave's code slice (ascending)

    // A fragments, all 4 point-tiles resident (A row = lane&15, k = kb..)
    bf16x8 Ahi[4][2], Alo[4][2];
#pragma unroll
    for (int pt = 0; pt < 4; ++pt) {
        int p = pt * 16 + m15;
        cvt8(&lds_x[p][kb],      Ahi[pt][0], Alo[pt][0]);
        cvt8(&lds_x[p][kb + 32], Ahi[pt][1], Alo[pt][1]);
    }

    float best[4][4];
    int   bestk[4][4];
#pragma unroll
    for (int pt = 0; pt < 4; ++pt)
#pragma unroll
        for (int r = 0; r < 4; ++r) { best[pt][r] = INFINITY; bestk[pt][r] = 0; }

    for (int ct = 0; ct < 16; ++ct) {
        const int code = c0w + ct * 16 + m15;          // B col = lane&15
        const float* ep = emb + (size_t)code * DIM + kb;
        float4 e0 = *(const float4*)ep;
        float4 e1 = *(const float4*)(ep + 4);
        float4 e2a = *(const float4*)(ep + 32);
        float4 e3 = *(const float4*)(ep + 36);

        // ||e||^2: 16 local squares, then sum the 4 k-slices (xor keeps m15)
        float sq = e0.x * e0.x;
        sq = fmaf(e0.y, e0.y, sq); sq = fmaf(e0.z, e0.z, sq); sq = fmaf(e0.w, e0.w, sq);
        sq = fmaf(e1.x, e1.x, sq); sq = fmaf(e1.y, e1.y, sq); sq = fmaf(e1.z, e1.z, sq); sq = fmaf(e1.w, e1.w, sq);
        sq = fmaf(e2a.x, e2a.x, sq); sq = fmaf(e2a.y, e2a.y, sq); sq = fmaf(e2a.z, e2a.z, sq); sq = fmaf(e2a.w, e2a.w, sq);
        sq = fmaf(e3.x, e3.x, sq); sq = fmaf(e3.y, e3.y, sq); sq = fmaf(e3.z, e3.z, sq); sq = fmaf(e3.w, e3.w, sq);
        sq += __shfl_xor(sq, 16, 64);
        sq += __shfl_xor(sq, 32, 64);
        const float e2v = sq;

        bf16x8 Bhi0, Blo0, Bhi1, Blo1;
        cvt8v(e0, e1, Bhi0, Blo0);
        cvt8v(e2a, e3, Bhi1, Blo1);

#pragma unroll
        for (int pt = 0; pt < 4; ++pt) {
            f32x4 acc = {0.f, 0.f, 0.f, 0.f};
            acc = __builtin_amdgcn_mfma_f32_16x16x32_bf16(Ahi[pt][0], Bhi0, acc, 0, 0, 0);
            acc = __builtin_amdgcn_mfma_f32_16x16x32_bf16(Ahi[pt][1], Bhi1, acc, 0, 0, 0);
            acc = __builtin_amdgcn_mfma_f32_16x16x32_bf16(Ahi[pt][0], Blo0, acc, 0, 0, 0);
            acc = __builtin_amdgcn_mfma_f32_16x16x32_bf16(Ahi[pt][1], Blo1, acc, 0, 0, 0);
            acc = __builtin_amdgcn_mfma_f32_16x16x32_bf16(Alo[pt][0], Bhi0, acc, 0, 0, 0);
            acc = __builtin_amdgcn_mfma_f32_16x16x32_bf16(Alo[pt][1], Bhi1, acc, 0, 0, 0);
#pragma unroll
            for (int r = 0; r < 4; ++r) {
                float dist = fmaf(-2.0f, acc[r], e2v);
                if (dist < best[pt][r]) { best[pt][r] = dist; bestk[pt][r] = code; }
            }
        }
    }

    // per-wave cross-lane argmin over 16 cols, lexicographic (dist, code)
#pragma unroll
    for (int pt = 0; pt < 4; ++pt) {
#pragma unroll
        for (int r = 0; r < 4; ++r) {
            unsigned u = __float_as_uint(best[pt][r]);
            u = (u & 0x80000000u) ? ~u : (u | 0x80000000u);   // monotone f32->u32
            unsigned long long key = ((unsigned long long)u << 32) | (unsigned)bestk[pt][r];
#pragma unroll
            for (int sm = 1; sm < 16; sm <<= 1) {
                unsigned long long o = __shfl_xor(key, sm, 16);
                key = (o < key) ? o : key;
            }
            if (m15 == 0) cand[wv][pt * 16 + g4 * 4 + r] = key;
        }
    }
    __syncthreads();

    if (tid < 64) {   // merge 4 wave-slices (ascending -> first-min tie-break)
        unsigned long long k0 = cand[0][tid];
#pragma unroll
        for (int s = 1; s < 4; ++s) {
            unsigned long long o = cand[s][tid];
            if (o < k0) k0 = o;
        }
        int idx = (int)(k0 & 0xFFFFFFFFull);
        s_idx[tid] = idx;
        out[OFF_IDX + P0 + tid] = (float)idx;
        atomicAdd(&hist[idx], 1u);
    }
    __syncthreads();

    // ---- q_ste + loss: wave wv owns dims [16wv,16wv+16); x from LDS ----
    {
        const int w = lane;
        const int myidx = s_idx[w];
        const float* eq = emb + (size_t)myidx * DIM + wv * 16;
        float* qb = out + OFF_Q + ((size_t)b * 64 + wv * 16) * 4096 + h * 64 + w;
        float lsum = 0.f;
#pragma unroll
        for (int dd = 0; dd < 16; ++dd) {
            float x = lds_x[w][wv * 16 + dd];
            float diff = eq[dd] - x;
            lsum = fmaf(diff, diff, lsum);
            qb[(size_t)dd * 4096] = x + diff;      // exact STE form; plain store
        }
        for (int off = 32; off > 0; off >>= 1) lsum += __shfl_down(lsum, off, 64);
        if (lane == 0) atomicAdd(loss_acc, lsum);
    }

    // ---- one-hot: wave wv owns rows [16wv,16wv+16); PLAIN f32x4 stores ----
    // (the single A/B variable vs r10: plain stores ack at L2, not HBM)
    {
        f32x4* enc4 = (f32x4*)(out + OFF_ENC + (unsigned long long)P0 * NCODE);
#pragma unroll
        for (int rr = 0; rr < 16; ++rr) {
            const int row = wv * 16 + rr;          // wave-uniform
            const int target = s_idx[row];
#pragma unroll
            for (int k = 0; k < 4; ++k) {
                const int j = k * 64 + lane;       // f32x4 index in row
                const int c0 = j * 4;
                f32x4 v;
                v.x = (c0 + 0 == target) ? 1.0f : 0.0f;
                v.y = (c0 + 1 == target) ? 1.0f : 0.0f;
                v.z = (c0 + 2 == target) ? 1.0f : 0.0f;
                v.w = (c0 + 3 == target) ? 1.0f : 0.0f;
                enc4[(size_t)row * 256 + j] = v;
            }
        }
    }
}

// ---------------- finalize: loss scalar + perplexity ----------------
__global__ __launch_bounds__(1024) void vq_finalize(const unsigned int* __restrict__ hist,
                                                    const float* __restrict__ loss_acc,
                                                    float* __restrict__ out) {
    int t = threadIdx.x;
    float c = (float)hist[t];
    float pv = c * (1.0f / (float)NPTS);
    float term = pv * logf(pv + 1e-10f);

    __shared__ float red[16];
    float s = term;
    for (int off = 32; off > 0; off >>= 1) s += __shfl_down(s, off, 64);
    if ((t & 63) == 0) red[t >> 6] = s;
    __syncthreads();
    if (t < 16) {
        float v = red[t];
        for (int off = 8; off > 0; off >>= 1) v += __shfl_down(v, off, 64);
        if (t == 0) {
            out[OFF_PERP] = expf(-v);
            out[OFF_LOSS] = 0.25f * loss_acc[0] * (1.0f / 4194304.0f);
        }
    }
}

extern "C" void kernel_launch(void* const* d_in, const int* in_sizes, int n_in,
                              void* d_out, int out_size, void* d_ws, size_t ws_size,
                              hipStream_t stream) {
    const float* in  = (const float*)d_in[0];   // (16,64,64,64) BCHW
    const float* emb = (const float*)d_in[1];   // (1024,64)
    float* out = (float*)d_out;

    // ws: [0..15] loss_acc f32 | [16..1039] hist u32  (atomics only; no bulk)
    float* ws_f = (float*)d_ws;
    float* loss_acc = ws_f;
    unsigned int* hist = (unsigned int*)d_ws + 16;

    (void)hipMemsetAsync(d_ws, 0, (16 + NCODE) * sizeof(float), stream);

    vq_fused<<<NPTS / 64, 256, 0, stream>>>(in, emb, out, hist, loss_acc);
    vq_finalize<<<1, 1024, 0, stream>>>(hist, loss_acc, out);
}